// Round 11
// baseline (172.454 us; speedup 1.0000x reference)
//
#include <hip/hip_runtime.h>
#include <math.h>

#define EPS 1e-6f
constexpr int B = 8, N = 2048, C = 256, R = 4;

typedef short bf16x8 __attribute__((ext_vector_type(8)));
typedef float f32x4 __attribute__((ext_vector_type(4)));

__device__ __forceinline__ float wred_sum(float v) {
  for (int d = 32; d; d >>= 1) v += __shfl_xor(v, d, 64);
  return v;
}
__device__ __forceinline__ unsigned short f2bf(float f) {
  unsigned int x = __float_as_uint(f);
  unsigned int r = x + 0x7FFFu + ((x >> 16) & 1u);
  return (unsigned short)(r >> 16);
}

// ww is pointwise given softmax denominator: wg*(ag*alloc + (1-ag)*exp(sw)/denw)
__device__ __forceinline__ float ww_inline(float sw, float al, float dw,
                                           float agv, float wgv) {
  return wgv * (agv * al + (1.f - agv) * (expf(sw) / dw));
}

// ---- K_pre: blocks 0..255 = sort-free alloc; blocks 256..1279 = phiw + denw atomics
__global__ __launch_bounds__(1024) void k_pre(const float* __restrict__ usage,
    const float* __restrict__ wwp, const float* __restrict__ fg,
    const float* __restrict__ rw, const float* __restrict__ mem,
    const float* __restrict__ wk, const float* __restrict__ wstr,
    float* __restrict__ alloc_, float* __restrict__ sw_, float* __restrict__ denw) {
  __shared__ float2 ulg[N];       // 16KB
  __shared__ float Sp[16][64];    // 4KB
  __shared__ float eacc[16];
  int blk = blockIdx.x;
  int t = threadIdx.x;
  if (blk < 256) {
    int b = blk >> 5, chunk = blk & 31;
    float gx = fg[b * R + 0], gy = fg[b * R + 1], gz = fg[b * R + 2], gw2 = fg[b * R + 3];
    for (int e = t; e < N; e += 1024) {
      float4 r4 = *(const float4*)&rw[(size_t)(b * N + e) * R];
      float psi = (1.f - gx * r4.x) * (1.f - gy * r4.y) * (1.f - gz * r4.z) * (1.f - gw2 * r4.w);
      float us = usage[b * N + e], w = wwp[b * N + e];
      float u = (us + w - us * w) * psi;
      ulg[e] = make_float2(u, log2f(u));
    }
    __syncthreads();
    int i = chunk * 64 + (t & 63);
    int jseg = t >> 6;            // 0..15
    float ui = ulg[i].x;
    float S = 0.f;
    int j0 = jseg * 128;
    #pragma unroll 4
    for (int jj = 0; jj < 128; jj++) {
      int j = j0 + jj;
      float2 v = ulg[j];
      bool sel = (v.x < ui) || (v.x == ui && j < i);
      S += sel ? v.y : 0.f;
    }
    Sp[jseg][t & 63] = S;
    __syncthreads();
    if (t < 64) {
      float tot = 0.f;
      #pragma unroll
      for (int s = 0; s < 16; s++) tot += Sp[s][t];
      int ii = chunk * 64 + t;
      alloc_[b * N + ii] = (1.f - ulg[ii].x) * exp2f(tot);
    }
  } else {
    int wv = t >> 6, lane = t & 63;
    int gw = (blk - 256) * 16 + wv;
    int b = gw >> 11, n = gw & (N - 1);
    float4 m4 = *(const float4*)&mem[(size_t)(b * N + n) * C + lane * 4];
    float4 k4 = *(const float4*)&wk[b * C + lane * 4];
    float dot = m4.x * k4.x + m4.y * k4.y + m4.z * k4.z + m4.w * k4.w;
    float nrm = m4.x * m4.x + m4.y * m4.y + m4.z * m4.z + m4.w * m4.w;
    float knr = k4.x * k4.x + k4.y * k4.y + k4.z * k4.z + k4.w * k4.w;
    for (int d = 32; d; d >>= 1) {
      dot += __shfl_xor(dot, d, 64);
      nrm += __shfl_xor(nrm, d, 64);
      knr += __shfl_xor(knr, d, 64);
    }
    if (lane == 0) {
      float phi = dot / (sqrtf(nrm) * sqrtf(knr) + EPS);
      float swv = phi * wstr[b];
      sw_[b * N + n] = swv;
      eacc[wv] = expf(swv);
    }
    __syncthreads();
    if (t == 0) {
      float s = 0.f;
      #pragma unroll
      for (int i = 0; i < 16; i++) s += eacc[i];
      atomicAdd(&denw[b], s);
    }
  }
}

// ---- K_cw: cwg[b][n][8] = [rw | ww*rw] (f32), cwfrag = B-fragments (bf16, MFMA
//      layout: lane=lg*16+col holds elem e for j=kk*32+lg*8+e), ST via atomics.
__global__ __launch_bounds__(512) void k_cw(const float* __restrict__ rw,
    const float* __restrict__ sw_, const float* __restrict__ alloc_,
    const float* __restrict__ denw, const float* __restrict__ ag,
    const float* __restrict__ wg, const float* __restrict__ prec,
    float* __restrict__ cwg, unsigned short* __restrict__ cwfrag,
    float* __restrict__ ST_) {
  __shared__ float red8[8][8];
  int blk = blockIdx.x, t = threadIdx.x;
  int b = blk >> 2, seg = blk & 3;
  int n = seg * 512 + t;
  int lane = t & 63, wv = t >> 6;
  float agv = ag[b], wgv = wg[b], dw = denw[b];
  float4 r4 = *(const float4*)&rw[(size_t)(b * N + n) * R];
  float w = ww_inline(sw_[b * N + n], alloc_[b * N + n], dw, agv, wgv);
  float pc = prec[b * N + n];
  float vals[8] = { r4.x, r4.y, r4.z, r4.w, w * r4.x, w * r4.y, w * r4.z, w * r4.w };
  *(float4*)&cwg[(size_t)(b * N + n) * 8] = make_float4(vals[0], vals[1], vals[2], vals[3]);
  *(float4*)&cwg[(size_t)(b * N + n) * 8 + 4] = make_float4(vals[4], vals[5], vals[6], vals[7]);
  // scatter to MFMA B-fragment layout
  {
    size_t base = (((size_t)(b * 64 + (n >> 5))) * 64 + ((n & 31) >> 3) * 16) * 8 + (n & 7);
    #pragma unroll
    for (int c = 0; c < 8; c++) cwfrag[base + (size_t)c * 8] = f2bf(vals[c]);
  }
  float a[8] = { pc * r4.x, pc * r4.y, pc * r4.z, pc * r4.w,
                 w * r4.x,  w * r4.y,  w * r4.z,  w * r4.w };
  #pragma unroll
  for (int r = 0; r < 8; r++) a[r] = wred_sum(a[r]);
  if (lane == 0) {
    #pragma unroll
    for (int r = 0; r < 8; r++) red8[wv][r] = a[r];
  }
  __syncthreads();
  if (t < 8) {
    float s = 0.f;
    #pragma unroll
    for (int i = 0; i < 8; i++) s += red8[i][t];
    atomicAdd(&ST_[b * 8 + t], s);
  }
}

// ---- K_mid: blocks [0,128) t via MFMA; [128,384) u scalar; [384,2432) phir
__global__ __launch_bounds__(512) void k_mid(const float* __restrict__ link,
    const float* __restrict__ rw, const float* __restrict__ sw_,
    const float* __restrict__ alloc_, const float* __restrict__ denw,
    const float* __restrict__ ag, const float* __restrict__ wg,
    const float* __restrict__ mem, const float* __restrict__ rk,
    const float* __restrict__ ev, const float* __restrict__ wvec,
    const float* __restrict__ rs, const float* __restrict__ cwg,
    const unsigned short* __restrict__ cwfrag,
    float* __restrict__ t_, float* __restrict__ upart, float* __restrict__ sr_,
    float* __restrict__ denr) {
  __shared__ float ri8l[64][8];      // (u-blocks)
  __shared__ float eacc[8][4];       // (phir)
  const int blk = blockIdx.x;
  const int t = threadIdx.x;
  const int lane = t & 63, wv = t >> 6;
  if (blk < 128) {
    // ======== t = link · CW8 via mfma_f32_16x16x32_bf16, one 16-row tile/wave
    const int g = blk * 8 + wv;          // global tile id, 1024 total
    const int b = g >> 7;
    const int i0 = (g & 127) * 16;
    f32x4 acc = { 0.f, 0.f, 0.f, 0.f };
    const float* ap = link + ((size_t)(b * N + i0 + (lane & 15))) * N + ((lane >> 4) * 8);
    const bf16x8* cfp = (const bf16x8*)cwfrag + (size_t)(b * 64) * 64 + lane;
    for (int kk = 0; kk < 64; kk++) {
      float4 a0 = *(const float4*)(ap + kk * 32);
      float4 a1 = *(const float4*)(ap + kk * 32 + 4);
      bf16x8 af;
      af[0] = (short)f2bf(a0.x); af[1] = (short)f2bf(a0.y);
      af[2] = (short)f2bf(a0.z); af[3] = (short)f2bf(a0.w);
      af[4] = (short)f2bf(a1.x); af[5] = (short)f2bf(a1.y);
      af[6] = (short)f2bf(a1.z); af[7] = (short)f2bf(a1.w);
      bf16x8 bfv = cfp[(size_t)kk * 64];
      acc = __builtin_amdgcn_mfma_f32_16x16x32_bf16(af, bfv, acc, 0, 0, 0);
    }
    // C layout: col=lane&15, row=(lane>>4)*4+reg  [m89-verified]
    const int col = lane & 15;
    if (col < 8) {
      const int rbase = (lane >> 4) * 4;
      #pragma unroll
      for (int reg = 0; reg < 4; reg++)
        t_[((size_t)(b * 8 + col)) * N + i0 + rbase + reg] = acc[reg];
    }
  } else if (blk < 384) {
    // ======== u scalar: 64-row strip, thread owns 4 columns (proven R5/R10 path)
    const int ub = blk - 128;
    const int b = ub >> 5;
    const int strip = ub & 31;
    const int i0 = strip * 64;
    const int jb = t * 4;
    ri8l[t >> 3][t & 7] = cwg[(size_t)(b * N + i0) * 8 + t];
    float uacc[4][8];
    #pragma unroll
    for (int k = 0; k < 4; k++) {
      #pragma unroll
      for (int r = 0; r < 8; r++) uacc[k][r] = 0.f;
    }
    __syncthreads();
    for (int ii = 0; ii < 64; ii += 4) {
      float4 La[4];
      #pragma unroll
      for (int m = 0; m < 4; m++)
        La[m] = *(const float4*)(link + (size_t)(b * N + i0 + ii + m) * N + jb);
      #pragma unroll
      for (int m = 0; m < 4; m++) {
        float lv[4] = { La[m].x, La[m].y, La[m].z, La[m].w };
        #pragma unroll
        for (int k = 0; k < 4; k++) {
          #pragma unroll
          for (int r = 0; r < 8; r++)
            uacc[k][r] = fmaf(lv[k], ri8l[ii + m][r], uacc[k][r]);
        }
      }
    }
    float* ubp = upart + ((size_t)(b * 32 + strip) * 8) * N;
    #pragma unroll
    for (int r = 0; r < 8; r++) {
      float4 v = { uacc[0][r], uacc[1][r], uacc[2][r], uacc[3][r] };
      *(float4*)(ubp + (size_t)r * N + jb) = v;
    }
  } else {
    // ======== phir: 8 rows per block + denr atomics ========
    int gw = (blk - 384) * 8 + wv;
    int b = gw >> 11, n = gw & (N - 1);
    const float agv = ag[b], wgv = wg[b], dw = denw[b];
    float w = ww_inline(sw_[b * N + n], alloc_[b * N + n], dw, agv, wgv);
    int c0i = lane * 4;
    float4 m4 = *(const float4*)&mem[(size_t)(b * N + n) * C + c0i];
    float4 e4 = *(const float4*)&ev[b * C + c0i];
    float4 v4 = *(const float4*)&wvec[b * C + c0i];
    float mn[4] = { m4.x * (1.f - w * e4.x) + w * v4.x,
                    m4.y * (1.f - w * e4.y) + w * v4.y,
                    m4.z * (1.f - w * e4.z) + w * v4.z,
                    m4.w * (1.f - w * e4.w) + w * v4.w };
    float dot[4] = { 0, 0, 0, 0 };
    float kn[4] = { 0, 0, 0, 0 };
    float nrm = 0.f;
    #pragma unroll
    for (int ci = 0; ci < 4; ci++) {
      float4 k4 = *(const float4*)&rk[(size_t)(b * C + c0i + ci) * R];
      dot[0] = fmaf(mn[ci], k4.x, dot[0]);
      dot[1] = fmaf(mn[ci], k4.y, dot[1]);
      dot[2] = fmaf(mn[ci], k4.z, dot[2]);
      dot[3] = fmaf(mn[ci], k4.w, dot[3]);
      kn[0] = fmaf(k4.x, k4.x, kn[0]);
      kn[1] = fmaf(k4.y, k4.y, kn[1]);
      kn[2] = fmaf(k4.z, k4.z, kn[2]);
      kn[3] = fmaf(k4.w, k4.w, kn[3]);
      nrm = fmaf(mn[ci], mn[ci], nrm);
    }
    for (int d = 32; d; d >>= 1) {
      dot[0] += __shfl_xor(dot[0], d, 64);
      dot[1] += __shfl_xor(dot[1], d, 64);
      dot[2] += __shfl_xor(dot[2], d, 64);
      dot[3] += __shfl_xor(dot[3], d, 64);
      kn[0] += __shfl_xor(kn[0], d, 64);
      kn[1] += __shfl_xor(kn[1], d, 64);
      kn[2] += __shfl_xor(kn[2], d, 64);
      kn[3] += __shfl_xor(kn[3], d, 64);
      nrm += __shfl_xor(nrm, d, 64);
    }
    if (lane == 0) {
      float mnorm = sqrtf(nrm);
      #pragma unroll
      for (int r = 0; r < 4; r++) {
        float phi = dot[r] / (mnorm * sqrtf(kn[r]) + EPS);
        float sv = phi * rs[b * R + r];
        sr_[(size_t)(b * R + r) * N + n] = sv;
        eacc[wv][r] = expf(sv);
      }
    }
    __syncthreads();
    if (t < 4) {
      float s = 0.f;
      #pragma unroll
      for (int i = 0; i < 8; i++) s += eacc[i][t];
      atomicAdd(&denr[b * R + t], s);
    }
  }
}

// ---- K_combread: strip-reduce u, rwn in LDS, then read_vectors partials
__global__ __launch_bounds__(256) void k_combread(const float* __restrict__ link,
    const float* __restrict__ sw_, const float* __restrict__ alloc_,
    const float* __restrict__ denw, const float* __restrict__ denr,
    const float* __restrict__ ag, const float* __restrict__ wg,
    const float* __restrict__ prec, const float* __restrict__ rw,
    const float* __restrict__ t_, const float* __restrict__ upart,
    const float* __restrict__ sr_, const float* __restrict__ ST_,
    const float* __restrict__ modes, const float* __restrict__ mem,
    const float* __restrict__ ev, const float* __restrict__ wvec,
    float* __restrict__ part_) {
  __shared__ float dgl[64], wloc[64], rwnl[4][64];
  __shared__ float red[4][64][4][4];   // 16KB
  const int blk = blockIdx.x;
  const int b = blk >> 5, chunk = blk & 31;
  const int n0 = chunk * 64;
  const int t = threadIdx.x;
  const int nl = t & 63, r = t >> 6;
  const int n = n0 + nl;
  const float agv = ag[b], wgv = wg[b], dw = denw[b];
  float u1 = 0.f, u2 = 0.f;
  const float* up = upart + ((size_t)(b * 32) * 8) * N;
  #pragma unroll 8
  for (int s = 0; s < 32; s++) {
    const float* p = up + ((size_t)s * 8) * N;
    u1 += p[(size_t)r * N + n];
    u2 += p[(size_t)(4 + r) * N + n];
  }
  float pc = prec[b * N + n];
  if (r == 0) {
    float w = ww_inline(sw_[b * N + n], alloc_[b * N + n], dw, agv, wgv);
    float L = link[((size_t)(b * N + n)) * N + n];
    dgl[nl] = (1.f - 2.f * w) * L + w * pc;
    wloc[nl] = w;
  }
  __syncthreads();
  {
    float w = wloc[nl], Dg = dgl[nl];
    float t1 = t_[(size_t)(b * 8 + r) * N + n];
    float t2 = t_[(size_t)(b * 8 + 4 + r) * N + n];
    float sv = sr_[(size_t)(b * R + r) * N + n];
    float cr = expf(sv) / denr[b * R + r];
    float rv = rw[(size_t)(b * N + n) * R + r];
    float S = ST_[b * 8 + r], T = ST_[b * 8 + 4 + r];
    float m0 = modes[(b * 3 + 0) * R + r], m1 = modes[(b * 3 + 1) * R + r],
          m2 = modes[(b * 3 + 2) * R + r];
    float fwd = (1.f - w) * t1 - t2 + w * S - Dg * rv;
    float bwd = (1.f - w) * u1 - u2 + pc * T - Dg * rv;
    rwnl[r][nl] = m0 * bwd + m1 * cr + m2 * fwd;
  }
  __syncthreads();
  const int sub = r, cg = nl;
  const int c0 = cg * 4;
  float4 e4 = *(const float4*)&ev[b * C + c0];
  float4 v4 = *(const float4*)&wvec[b * C + c0];
  float acc[4][4];
  #pragma unroll
  for (int ci = 0; ci < 4; ci++) {
    #pragma unroll
    for (int rr = 0; rr < 4; rr++) acc[ci][rr] = 0.f;
  }
  for (int m = 0; m < 16; m++) {
    int row = sub * 16 + m;
    int nn = n0 + row;
    float w = wloc[row];
    float4 m4 = *(const float4*)&mem[(size_t)(b * N + nn) * C + c0];
    float mn[4] = { m4.x * (1.f - w * e4.x) + w * v4.x,
                    m4.y * (1.f - w * e4.y) + w * v4.y,
                    m4.z * (1.f - w * e4.z) + w * v4.z,
                    m4.w * (1.f - w * e4.w) + w * v4.w };
    float rv[4] = { rwnl[0][row], rwnl[1][row], rwnl[2][row], rwnl[3][row] };
    #pragma unroll
    for (int ci = 0; ci < 4; ci++) {
      #pragma unroll
      for (int rr = 0; rr < 4; rr++) acc[ci][rr] = fmaf(mn[ci], rv[rr], acc[ci][rr]);
    }
  }
  #pragma unroll
  for (int ci = 0; ci < 4; ci++) {
    #pragma unroll
    for (int rr = 0; rr < 4; rr++) red[sub][cg][ci][rr] = acc[ci][rr];
  }
  __syncthreads();
  if (sub == 0) {
    #pragma unroll
    for (int ci = 0; ci < 4; ci++) {
      #pragma unroll
      for (int rr = 0; rr < 4; rr++) {
        float s = red[0][cg][ci][rr] + red[1][cg][ci][rr] +
                  red[2][cg][ci][rr] + red[3][cg][ci][rr];
        part_[((size_t)blk * C + (c0 + ci)) * R + rr] = s;
      }
    }
  }
}

// ---- K_final: reduce 32 chunk partials -> out [B][C][R]
__global__ void k_final(const float* __restrict__ part_, float* __restrict__ out) {
  int idx = blockIdx.x * 256 + threadIdx.x;
  if (idx >= B * C * R) return;
  int b = idx / (C * R), cr = idx % (C * R);
  float s = 0.f;
  for (int ch = 0; ch < 32; ch++) s += part_[(size_t)(b * 32 + ch) * C * R + cr];
  out[idx] = s;
}

extern "C" void kernel_launch(void* const* d_in, const int* in_sizes, int n_in,
                              void* d_out, int out_size, void* d_ws, size_t ws_size,
                              hipStream_t stream) {
  const float* mem   = (const float*)d_in[0];
  const float* link  = (const float*)d_in[1];
  const float* usage = (const float*)d_in[2];
  const float* rw    = (const float*)d_in[3];
  const float* wwp   = (const float*)d_in[4];
  const float* prec  = (const float*)d_in[5];
  const float* rk    = (const float*)d_in[6];
  const float* rs    = (const float*)d_in[7];
  const float* wk    = (const float*)d_in[8];
  const float* wstr  = (const float*)d_in[9];
  const float* fg    = (const float*)d_in[10];
  const float* ag    = (const float*)d_in[11];
  const float* wg    = (const float*)d_in[12];
  const float* wvec  = (const float*)d_in[13];
  const float* ev    = (const float*)d_in[14];
  const float* modes = (const float*)d_in[15];
  float* out = (float*)d_out;

  float* W = (float*)d_ws;
  float* denw  = W;                   // 8
  float* denr  = W + 8;               // 32
  float* ST_   = W + 64;              // 64   (zeroed below)
  float* alloc_= W + 128;             // B*N
  float* sw_   = alloc_ + B * N;      // B*N
  float* t_    = sw_ + B * N;         // B*8*N
  float* sr_   = t_ + B * 8 * N;      // B*R*N
  float* part_ = sr_ + B * R * N;     // B*32*C*R
  float* cwg   = part_ + B * 32 * C * R;  // B*N*8
  float* upart = cwg + B * N * 8;     // B*32*8*N = 16MB
  unsigned short* cwfrag = (unsigned short*)(upart + (size_t)B * 32 * 8 * N);  // B*64*64*8 u16 = 512KB

  (void)hipMemsetAsync(W, 0, 128 * sizeof(float), stream);
  (void)hipMemsetAsync(cwfrag, 0, (size_t)B * 64 * 64 * 8 * sizeof(unsigned short), stream);
  k_pre<<<256 + (B * N) / 16, 1024, 0, stream>>>(usage, wwp, fg, rw, mem, wk, wstr,
                                                 alloc_, sw_, denw);
  k_cw<<<B * 4, 512, 0, stream>>>(rw, sw_, alloc_, denw, ag, wg, prec, cwg, cwfrag, ST_);
  k_mid<<<128 + 256 + (B * N) / 8, 512, 0, stream>>>(link, rw, sw_, alloc_, denw, ag, wg,
                                                     mem, rk, ev, wvec, rs, cwg, cwfrag,
                                                     t_, upart, sr_, denr);
  k_combread<<<B * 32, 256, 0, stream>>>(link, sw_, alloc_, denw, denr, ag, wg, prec,
                                         rw, t_, upart, sr_, ST_, modes, mem, ev,
                                         wvec, part_);
  k_final<<<(B * C * R) / 256, 256, 0, stream>>>(part_, out);
}

// Round 12
// 166.716 us; speedup vs baseline: 1.0344x; 1.0344x over previous
//
#include <hip/hip_runtime.h>
#include <math.h>

#define EPS 1e-6f
constexpr int B = 8, N = 2048, C = 256, R = 4;

typedef short bf16x8 __attribute__((ext_vector_type(8)));
typedef float f32x4 __attribute__((ext_vector_type(4)));

__device__ __forceinline__ float wred_sum(float v) {
  for (int d = 32; d; d >>= 1) v += __shfl_xor(v, d, 64);
  return v;
}
__device__ __forceinline__ unsigned short f2bf(float f) {
  unsigned int x = __float_as_uint(f);
  unsigned int r = x + 0x7FFFu + ((x >> 16) & 1u);
  return (unsigned short)(r >> 16);
}

// ww is pointwise given softmax denominator: wg*(ag*alloc + (1-ag)*exp(sw)/denw)
__device__ __forceinline__ float ww_inline(float sw, float al, float dw,
                                           float agv, float wgv) {
  return wgv * (agv * al + (1.f - agv) * (expf(sw) / dw));
}

// ---- K_pre: blocks 0..255 = sort-free alloc; blocks 256..1279 = phiw + denw atomics
__global__ __launch_bounds__(1024) void k_pre(const float* __restrict__ usage,
    const float* __restrict__ wwp, const float* __restrict__ fg,
    const float* __restrict__ rw, const float* __restrict__ mem,
    const float* __restrict__ wk, const float* __restrict__ wstr,
    float* __restrict__ alloc_, float* __restrict__ sw_, float* __restrict__ denw) {
  __shared__ float2 ulg[N];       // 16KB
  __shared__ float Sp[16][64];    // 4KB
  __shared__ float eacc[16];
  int blk = blockIdx.x;
  int t = threadIdx.x;
  if (blk < 256) {
    int b = blk >> 5, chunk = blk & 31;
    float gx = fg[b * R + 0], gy = fg[b * R + 1], gz = fg[b * R + 2], gw2 = fg[b * R + 3];
    for (int e = t; e < N; e += 1024) {
      float4 r4 = *(const float4*)&rw[(size_t)(b * N + e) * R];
      float psi = (1.f - gx * r4.x) * (1.f - gy * r4.y) * (1.f - gz * r4.z) * (1.f - gw2 * r4.w);
      float us = usage[b * N + e], w = wwp[b * N + e];
      float u = (us + w - us * w) * psi;
      ulg[e] = make_float2(u, log2f(u));
    }
    __syncthreads();
    int i = chunk * 64 + (t & 63);
    int jseg = t >> 6;            // 0..15
    float ui = ulg[i].x;
    float S = 0.f;
    int j0 = jseg * 128;
    #pragma unroll 4
    for (int jj = 0; jj < 128; jj++) {
      int j = j0 + jj;
      float2 v = ulg[j];
      bool sel = (v.x < ui) || (v.x == ui && j < i);
      S += sel ? v.y : 0.f;
    }
    Sp[jseg][t & 63] = S;
    __syncthreads();
    if (t < 64) {
      float tot = 0.f;
      #pragma unroll
      for (int s = 0; s < 16; s++) tot += Sp[s][t];
      int ii = chunk * 64 + t;
      alloc_[b * N + ii] = (1.f - ulg[ii].x) * exp2f(tot);
    }
  } else {
    int wv = t >> 6, lane = t & 63;
    int gw = (blk - 256) * 16 + wv;
    int b = gw >> 11, n = gw & (N - 1);
    float4 m4 = *(const float4*)&mem[(size_t)(b * N + n) * C + lane * 4];
    float4 k4 = *(const float4*)&wk[b * C + lane * 4];
    float dot = m4.x * k4.x + m4.y * k4.y + m4.z * k4.z + m4.w * k4.w;
    float nrm = m4.x * m4.x + m4.y * m4.y + m4.z * m4.z + m4.w * m4.w;
    float knr = k4.x * k4.x + k4.y * k4.y + k4.z * k4.z + k4.w * k4.w;
    for (int d = 32; d; d >>= 1) {
      dot += __shfl_xor(dot, d, 64);
      nrm += __shfl_xor(nrm, d, 64);
      knr += __shfl_xor(knr, d, 64);
    }
    if (lane == 0) {
      float phi = dot / (sqrtf(nrm) * sqrtf(knr) + EPS);
      float swv = phi * wstr[b];
      sw_[b * N + n] = swv;
      eacc[wv] = expf(swv);
    }
    __syncthreads();
    if (t == 0) {
      float s = 0.f;
      #pragma unroll
      for (int i = 0; i < 16; i++) s += eacc[i];
      atomicAdd(&denw[b], s);
    }
  }
}

// ---- K_cw: cwg[b][n][8] = [rw | ww*rw] (f32), cwfrag = B-fragments (bf16, MFMA
//      layout: lane=lg*16+col holds elem e for j=kk*32+lg*8+e), ST via atomics.
__global__ __launch_bounds__(512) void k_cw(const float* __restrict__ rw,
    const float* __restrict__ sw_, const float* __restrict__ alloc_,
    const float* __restrict__ denw, const float* __restrict__ ag,
    const float* __restrict__ wg, const float* __restrict__ prec,
    float* __restrict__ cwg, unsigned short* __restrict__ cwfrag,
    float* __restrict__ ST_) {
  __shared__ float red8[8][8];
  int blk = blockIdx.x, t = threadIdx.x;
  int b = blk >> 2, seg = blk & 3;
  int n = seg * 512 + t;
  int lane = t & 63, wv = t >> 6;
  float agv = ag[b], wgv = wg[b], dw = denw[b];
  float4 r4 = *(const float4*)&rw[(size_t)(b * N + n) * R];
  float w = ww_inline(sw_[b * N + n], alloc_[b * N + n], dw, agv, wgv);
  float pc = prec[b * N + n];
  float vals[8] = { r4.x, r4.y, r4.z, r4.w, w * r4.x, w * r4.y, w * r4.z, w * r4.w };
  *(float4*)&cwg[(size_t)(b * N + n) * 8] = make_float4(vals[0], vals[1], vals[2], vals[3]);
  *(float4*)&cwg[(size_t)(b * N + n) * 8 + 4] = make_float4(vals[4], vals[5], vals[6], vals[7]);
  // scatter to MFMA B-fragment layout
  {
    size_t base = (((size_t)(b * 64 + (n >> 5))) * 64 + ((n & 31) >> 3) * 16) * 8 + (n & 7);
    #pragma unroll
    for (int c = 0; c < 8; c++) cwfrag[base + (size_t)c * 8] = f2bf(vals[c]);
  }
  float a[8] = { pc * r4.x, pc * r4.y, pc * r4.z, pc * r4.w,
                 w * r4.x,  w * r4.y,  w * r4.z,  w * r4.w };
  #pragma unroll
  for (int r = 0; r < 8; r++) a[r] = wred_sum(a[r]);
  if (lane == 0) {
    #pragma unroll
    for (int r = 0; r < 8; r++) red8[wv][r] = a[r];
  }
  __syncthreads();
  if (t < 8) {
    float s = 0.f;
    #pragma unroll
    for (int i = 0; i < 8; i++) s += red8[i][t];
    atomicAdd(&ST_[b * 8 + t], s);
  }
}

// ---- K_mid: blocks [0,128) t via MFMA + LDS-staged A; [128,384) u scalar;
//             [384,2432) phir
__global__ __launch_bounds__(512) void k_mid(const float* __restrict__ link,
    const float* __restrict__ rw, const float* __restrict__ sw_,
    const float* __restrict__ alloc_, const float* __restrict__ denw,
    const float* __restrict__ ag, const float* __restrict__ wg,
    const float* __restrict__ mem, const float* __restrict__ rk,
    const float* __restrict__ ev, const float* __restrict__ wvec,
    const float* __restrict__ rs, const float* __restrict__ cwg,
    const unsigned short* __restrict__ cwfrag,
    float* __restrict__ t_, float* __restrict__ upart, float* __restrict__ sr_,
    float* __restrict__ denr) {
  __shared__ unsigned short AT[2][128][72];  // 36KB, 72-pad: 16B-aligned rows
  __shared__ float ri8l[64][8];              // (u-blocks)
  __shared__ float eacc[8][4];               // (phir)
  const int blk = blockIdx.x;
  const int t = threadIdx.x;
  const int lane = t & 63, wv = t >> 6;
  if (blk < 128) {
    // ======== t = link · CW8 via MFMA; A coalesced-staged through LDS ========
    const int b = blk >> 4;
    const int i0 = (blk & 15) * 128;
    const int wrow = wv * 16;
    const int scg = t & 15;          // staging col-group (4 cols)
    const int srow = t >> 4;         // staging row base (0..31)
    const float* lsrc = link + (size_t)(b * N + i0 + srow) * N + scg * 4;
    const size_t cwbase = (size_t)b * 64 * 64 * 8;   // shorts
    f32x4 acc = { 0.f, 0.f, 0.f, 0.f };

#define STAGE(kc_, buf_)                                                      \
    {                                                                         \
      _Pragma("unroll") for (int p = 0; p < 4; p++) {                         \
        float4 v = *(const float4*)(lsrc + (size_t)(p * 32) * N + (kc_) * 64);\
        ushort4 h;                                                            \
        h.x = f2bf(v.x); h.y = f2bf(v.y); h.z = f2bf(v.z); h.w = f2bf(v.w);   \
        *(ushort4*)&AT[buf_][srow + p * 32][scg * 4] = h;                     \
      }                                                                       \
    }

    STAGE(0, 0);
    __syncthreads();
    for (int kc = 0; kc < 32; kc++) {
      const int cur = kc & 1;
      if (kc < 31) STAGE(kc + 1, cur ^ 1);
      #pragma unroll
      for (int kk = 0; kk < 2; kk++) {
        bf16x8 af = *(const bf16x8*)&AT[cur][wrow + (lane & 15)][kk * 32 + (lane >> 4) * 8];
        bf16x8 bfv = *(const bf16x8*)&cwfrag[cwbase + ((size_t)(kc * 2 + kk) * 64 + lane) * 8];
        acc = __builtin_amdgcn_mfma_f32_16x16x32_bf16(af, bfv, acc, 0, 0, 0);
      }
      __syncthreads();
    }
    // C layout: col=lane&15, row=(lane>>4)*4+reg  [m89-verified]
    const int col = lane & 15;
    if (col < 8) {
      const int rbase = (lane >> 4) * 4;
      #pragma unroll
      for (int reg = 0; reg < 4; reg++)
        t_[((size_t)(b * 8 + col)) * N + i0 + wrow + rbase + reg] = acc[reg];
    }
#undef STAGE
  } else if (blk < 384) {
    // ======== u scalar: 64-row strip, thread owns 4 columns (proven path)
    const int ub = blk - 128;
    const int b = ub >> 5;
    const int strip = ub & 31;
    const int i0 = strip * 64;
    const int jb = t * 4;
    ri8l[t >> 3][t & 7] = cwg[(size_t)(b * N + i0) * 8 + t];
    float uacc[4][8];
    #pragma unroll
    for (int k = 0; k < 4; k++) {
      #pragma unroll
      for (int r = 0; r < 8; r++) uacc[k][r] = 0.f;
    }
    __syncthreads();
    for (int ii = 0; ii < 64; ii += 4) {
      float4 La[4];
      #pragma unroll
      for (int m = 0; m < 4; m++)
        La[m] = *(const float4*)(link + (size_t)(b * N + i0 + ii + m) * N + jb);
      #pragma unroll
      for (int m = 0; m < 4; m++) {
        float lv[4] = { La[m].x, La[m].y, La[m].z, La[m].w };
        #pragma unroll
        for (int k = 0; k < 4; k++) {
          #pragma unroll
          for (int r = 0; r < 8; r++)
            uacc[k][r] = fmaf(lv[k], ri8l[ii + m][r], uacc[k][r]);
        }
      }
    }
    float* ubp = upart + ((size_t)(b * 32 + strip) * 8) * N;
    #pragma unroll
    for (int r = 0; r < 8; r++) {
      float4 v = { uacc[0][r], uacc[1][r], uacc[2][r], uacc[3][r] };
      *(float4*)(ubp + (size_t)r * N + jb) = v;
    }
  } else {
    // ======== phir: 8 rows per block + denr atomics ========
    int gw = (blk - 384) * 8 + wv;
    int b = gw >> 11, n = gw & (N - 1);
    const float agv = ag[b], wgv = wg[b], dw = denw[b];
    float w = ww_inline(sw_[b * N + n], alloc_[b * N + n], dw, agv, wgv);
    int c0i = lane * 4;
    float4 m4 = *(const float4*)&mem[(size_t)(b * N + n) * C + c0i];
    float4 e4 = *(const float4*)&ev[b * C + c0i];
    float4 v4 = *(const float4*)&wvec[b * C + c0i];
    float mn[4] = { m4.x * (1.f - w * e4.x) + w * v4.x,
                    m4.y * (1.f - w * e4.y) + w * v4.y,
                    m4.z * (1.f - w * e4.z) + w * v4.z,
                    m4.w * (1.f - w * e4.w) + w * v4.w };
    float dot[4] = { 0, 0, 0, 0 };
    float kn[4] = { 0, 0, 0, 0 };
    float nrm = 0.f;
    #pragma unroll
    for (int ci = 0; ci < 4; ci++) {
      float4 k4 = *(const float4*)&rk[(size_t)(b * C + c0i + ci) * R];
      dot[0] = fmaf(mn[ci], k4.x, dot[0]);
      dot[1] = fmaf(mn[ci], k4.y, dot[1]);
      dot[2] = fmaf(mn[ci], k4.z, dot[2]);
      dot[3] = fmaf(mn[ci], k4.w, dot[3]);
      kn[0] = fmaf(k4.x, k4.x, kn[0]);
      kn[1] = fmaf(k4.y, k4.y, kn[1]);
      kn[2] = fmaf(k4.z, k4.z, kn[2]);
      kn[3] = fmaf(k4.w, k4.w, kn[3]);
      nrm = fmaf(mn[ci], mn[ci], nrm);
    }
    for (int d = 32; d; d >>= 1) {
      dot[0] += __shfl_xor(dot[0], d, 64);
      dot[1] += __shfl_xor(dot[1], d, 64);
      dot[2] += __shfl_xor(dot[2], d, 64);
      dot[3] += __shfl_xor(dot[3], d, 64);
      kn[0] += __shfl_xor(kn[0], d, 64);
      kn[1] += __shfl_xor(kn[1], d, 64);
      kn[2] += __shfl_xor(kn[2], d, 64);
      kn[3] += __shfl_xor(kn[3], d, 64);
      nrm += __shfl_xor(nrm, d, 64);
    }
    if (lane == 0) {
      float mnorm = sqrtf(nrm);
      #pragma unroll
      for (int r = 0; r < 4; r++) {
        float phi = dot[r] / (mnorm * sqrtf(kn[r]) + EPS);
        float sv = phi * rs[b * R + r];
        sr_[(size_t)(b * R + r) * N + n] = sv;
        eacc[wv][r] = expf(sv);
      }
    }
    __syncthreads();
    if (t < 4) {
      float s = 0.f;
      #pragma unroll
      for (int i = 0; i < 8; i++) s += eacc[i][t];
      atomicAdd(&denr[b * R + t], s);
    }
  }
}

// ---- K_combread: strip-reduce u, rwn in LDS, then read_vectors partials
__global__ __launch_bounds__(256) void k_combread(const float* __restrict__ link,
    const float* __restrict__ sw_, const float* __restrict__ alloc_,
    const float* __restrict__ denw, const float* __restrict__ denr,
    const float* __restrict__ ag, const float* __restrict__ wg,
    const float* __restrict__ prec, const float* __restrict__ rw,
    const float* __restrict__ t_, const float* __restrict__ upart,
    const float* __restrict__ sr_, const float* __restrict__ ST_,
    const float* __restrict__ modes, const float* __restrict__ mem,
    const float* __restrict__ ev, const float* __restrict__ wvec,
    float* __restrict__ part_) {
  __shared__ float dgl[64], wloc[64], rwnl[4][64];
  __shared__ float red[4][64][4][4];   // 16KB
  const int blk = blockIdx.x;
  const int b = blk >> 5, chunk = blk & 31;
  const int n0 = chunk * 64;
  const int t = threadIdx.x;
  const int nl = t & 63, r = t >> 6;
  const int n = n0 + nl;
  const float agv = ag[b], wgv = wg[b], dw = denw[b];
  float u1 = 0.f, u2 = 0.f;
  const float* up = upart + ((size_t)(b * 32) * 8) * N;
  #pragma unroll 8
  for (int s = 0; s < 32; s++) {
    const float* p = up + ((size_t)s * 8) * N;
    u1 += p[(size_t)r * N + n];
    u2 += p[(size_t)(4 + r) * N + n];
  }
  float pc = prec[b * N + n];
  if (r == 0) {
    float w = ww_inline(sw_[b * N + n], alloc_[b * N + n], dw, agv, wgv);
    float L = link[((size_t)(b * N + n)) * N + n];
    dgl[nl] = (1.f - 2.f * w) * L + w * pc;
    wloc[nl] = w;
  }
  __syncthreads();
  {
    float w = wloc[nl], Dg = dgl[nl];
    float t1 = t_[(size_t)(b * 8 + r) * N + n];
    float t2 = t_[(size_t)(b * 8 + 4 + r) * N + n];
    float sv = sr_[(size_t)(b * R + r) * N + n];
    float cr = expf(sv) / denr[b * R + r];
    float rv = rw[(size_t)(b * N + n) * R + r];
    float S = ST_[b * 8 + r], T = ST_[b * 8 + 4 + r];
    float m0 = modes[(b * 3 + 0) * R + r], m1 = modes[(b * 3 + 1) * R + r],
          m2 = modes[(b * 3 + 2) * R + r];
    float fwd = (1.f - w) * t1 - t2 + w * S - Dg * rv;
    float bwd = (1.f - w) * u1 - u2 + pc * T - Dg * rv;
    rwnl[r][nl] = m0 * bwd + m1 * cr + m2 * fwd;
  }
  __syncthreads();
  const int sub = r, cg = nl;
  const int c0 = cg * 4;
  float4 e4 = *(const float4*)&ev[b * C + c0];
  float4 v4 = *(const float4*)&wvec[b * C + c0];
  float acc[4][4];
  #pragma unroll
  for (int ci = 0; ci < 4; ci++) {
    #pragma unroll
    for (int rr = 0; rr < 4; rr++) acc[ci][rr] = 0.f;
  }
  for (int m = 0; m < 16; m++) {
    int row = sub * 16 + m;
    int nn = n0 + row;
    float w = wloc[row];
    float4 m4 = *(const float4*)&mem[(size_t)(b * N + nn) * C + c0];
    float mn[4] = { m4.x * (1.f - w * e4.x) + w * v4.x,
                    m4.y * (1.f - w * e4.y) + w * v4.y,
                    m4.z * (1.f - w * e4.z) + w * v4.z,
                    m4.w * (1.f - w * e4.w) + w * v4.w };
    float rv[4] = { rwnl[0][row], rwnl[1][row], rwnl[2][row], rwnl[3][row] };
    #pragma unroll
    for (int ci = 0; ci < 4; ci++) {
      #pragma unroll
      for (int rr = 0; rr < 4; rr++) acc[ci][rr] = fmaf(mn[ci], rv[rr], acc[ci][rr]);
    }
  }
  #pragma unroll
  for (int ci = 0; ci < 4; ci++) {
    #pragma unroll
    for (int rr = 0; rr < 4; rr++) red[sub][cg][ci][rr] = acc[ci][rr];
  }
  __syncthreads();
  if (sub == 0) {
    #pragma unroll
    for (int ci = 0; ci < 4; ci++) {
      #pragma unroll
      for (int rr = 0; rr < 4; rr++) {
        float s = red[0][cg][ci][rr] + red[1][cg][ci][rr] +
                  red[2][cg][ci][rr] + red[3][cg][ci][rr];
        part_[((size_t)blk * C + (c0 + ci)) * R + rr] = s;
      }
    }
  }
}

// ---- K_final: reduce 32 chunk partials -> out [B][C][R]
__global__ void k_final(const float* __restrict__ part_, float* __restrict__ out) {
  int idx = blockIdx.x * 256 + threadIdx.x;
  if (idx >= B * C * R) return;
  int b = idx / (C * R), cr = idx % (C * R);
  float s = 0.f;
  for (int ch = 0; ch < 32; ch++) s += part_[(size_t)(b * 32 + ch) * C * R + cr];
  out[idx] = s;
}

extern "C" void kernel_launch(void* const* d_in, const int* in_sizes, int n_in,
                              void* d_out, int out_size, void* d_ws, size_t ws_size,
                              hipStream_t stream) {
  const float* mem   = (const float*)d_in[0];
  const float* link  = (const float*)d_in[1];
  const float* usage = (const float*)d_in[2];
  const float* rw    = (const float*)d_in[3];
  const float* wwp   = (const float*)d_in[4];
  const float* prec  = (const float*)d_in[5];
  const float* rk    = (const float*)d_in[6];
  const float* rs    = (const float*)d_in[7];
  const float* wk    = (const float*)d_in[8];
  const float* wstr  = (const float*)d_in[9];
  const float* fg    = (const float*)d_in[10];
  const float* ag    = (const float*)d_in[11];
  const float* wg    = (const float*)d_in[12];
  const float* wvec  = (const float*)d_in[13];
  const float* ev    = (const float*)d_in[14];
  const float* modes = (const float*)d_in[15];
  float* out = (float*)d_out;

  float* W = (float*)d_ws;
  float* denw  = W;                   // 8
  float* denr  = W + 8;               // 32
  float* ST_   = W + 64;              // 64   (zeroed below)
  float* alloc_= W + 128;             // B*N
  float* sw_   = alloc_ + B * N;      // B*N
  float* t_    = sw_ + B * N;         // B*8*N
  float* sr_   = t_ + B * 8 * N;      // B*R*N
  float* part_ = sr_ + B * R * N;     // B*32*C*R
  float* cwg   = part_ + B * 32 * C * R;  // B*N*8
  float* upart = cwg + B * N * 8;     // B*32*8*N = 16MB
  unsigned short* cwfrag = (unsigned short*)(upart + (size_t)B * 32 * 8 * N);  // 512KB

  (void)hipMemsetAsync(W, 0, 128 * sizeof(float), stream);
  (void)hipMemsetAsync(cwfrag, 0, (size_t)B * 64 * 64 * 8 * sizeof(unsigned short), stream);
  k_pre<<<256 + (B * N) / 16, 1024, 0, stream>>>(usage, wwp, fg, rw, mem, wk, wstr,
                                                 alloc_, sw_, denw);
  k_cw<<<B * 4, 512, 0, stream>>>(rw, sw_, alloc_, denw, ag, wg, prec, cwg, cwfrag, ST_);
  k_mid<<<128 + 256 + (B * N) / 8, 512, 0, stream>>>(link, rw, sw_, alloc_, denw, ag, wg,
                                                     mem, rk, ev, wvec, rs, cwg, cwfrag,
                                                     t_, upart, sr_, denr);
  k_combread<<<B * 32, 256, 0, stream>>>(link, sw_, alloc_, denw, denr, ag, wg, prec,
                                         rw, t_, upart, sr_, ST_, modes, mem, ev,
                                         wvec, part_);
  k_final<<<(B * C * R) / 256, 256, 0, stream>>>(part_, out);
}

// Round 13
// 145.583 us; speedup vs baseline: 1.1846x; 1.1452x over previous
//
#include <hip/hip_runtime.h>
#include <math.h>

#define EPS 1e-6f
constexpr int B = 8, N = 2048, C = 256, R = 4;

__device__ __forceinline__ float wred_sum(float v) {
  for (int d = 32; d; d >>= 1) v += __shfl_xor(v, d, 64);
  return v;
}

// ww is pointwise given softmax denominator: wg*(ag*alloc + (1-ag)*exp(sw)/denw)
__device__ __forceinline__ float ww_inline(float sw, float al, float dw,
                                           float agv, float wgv) {
  return wgv * (agv * al + (1.f - agv) * (expf(sw) / dw));
}

// ---- K_pre: blocks 0..255 = sort-free alloc; blocks 256..1279 = phiw + denw atomics
__global__ __launch_bounds__(1024) void k_pre(const float* __restrict__ usage,
    const float* __restrict__ wwp, const float* __restrict__ fg,
    const float* __restrict__ rw, const float* __restrict__ mem,
    const float* __restrict__ wk, const float* __restrict__ wstr,
    float* __restrict__ alloc_, float* __restrict__ sw_, float* __restrict__ denw) {
  __shared__ float2 ulg[N];       // 16KB
  __shared__ float Sp[16][64];    // 4KB
  __shared__ float eacc[16];
  int blk = blockIdx.x;
  int t = threadIdx.x;
  if (blk < 256) {
    int b = blk >> 5, chunk = blk & 31;
    float gx = fg[b * R + 0], gy = fg[b * R + 1], gz = fg[b * R + 2], gw2 = fg[b * R + 3];
    for (int e = t; e < N; e += 1024) {
      float4 r4 = *(const float4*)&rw[(size_t)(b * N + e) * R];
      float psi = (1.f - gx * r4.x) * (1.f - gy * r4.y) * (1.f - gz * r4.z) * (1.f - gw2 * r4.w);
      float us = usage[b * N + e], w = wwp[b * N + e];
      float u = (us + w - us * w) * psi;
      ulg[e] = make_float2(u, log2f(u));
    }
    __syncthreads();
    int i = chunk * 64 + (t & 63);
    int jseg = t >> 6;            // 0..15
    float ui = ulg[i].x;
    float S = 0.f;
    int j0 = jseg * 128;
    #pragma unroll 4
    for (int jj = 0; jj < 128; jj++) {
      int j = j0 + jj;
      float2 v = ulg[j];
      bool sel = (v.x < ui) || (v.x == ui && j < i);
      S += sel ? v.y : 0.f;
    }
    Sp[jseg][t & 63] = S;
    __syncthreads();
    if (t < 64) {
      float tot = 0.f;
      #pragma unroll
      for (int s = 0; s < 16; s++) tot += Sp[s][t];
      int ii = chunk * 64 + t;
      alloc_[b * N + ii] = (1.f - ulg[ii].x) * exp2f(tot);
    }
  } else {
    int wv = t >> 6, lane = t & 63;
    int gw = (blk - 256) * 16 + wv;
    int b = gw >> 11, n = gw & (N - 1);
    float4 m4 = *(const float4*)&mem[(size_t)(b * N + n) * C + lane * 4];
    float4 k4 = *(const float4*)&wk[b * C + lane * 4];
    float dot = m4.x * k4.x + m4.y * k4.y + m4.z * k4.z + m4.w * k4.w;
    float nrm = m4.x * m4.x + m4.y * m4.y + m4.z * m4.z + m4.w * m4.w;
    float knr = k4.x * k4.x + k4.y * k4.y + k4.z * k4.z + k4.w * k4.w;
    for (int d = 32; d; d >>= 1) {
      dot += __shfl_xor(dot, d, 64);
      nrm += __shfl_xor(nrm, d, 64);
      knr += __shfl_xor(knr, d, 64);
    }
    if (lane == 0) {
      float phi = dot / (sqrtf(nrm) * sqrtf(knr) + EPS);
      float swv = phi * wstr[b];
      sw_[b * N + n] = swv;
      eacc[wv] = expf(swv);
    }
    __syncthreads();
    if (t == 0) {
      float s = 0.f;
      #pragma unroll
      for (int i = 0; i < 16; i++) s += eacc[i];
      atomicAdd(&denw[b], s);
    }
  }
}

// ---- K_cw: cwg[b][n][8] = [rw | ww*rw] (f32); ST via atomics.
__global__ __launch_bounds__(512) void k_cw(const float* __restrict__ rw,
    const float* __restrict__ sw_, const float* __restrict__ alloc_,
    const float* __restrict__ denw, const float* __restrict__ ag,
    const float* __restrict__ wg, const float* __restrict__ prec,
    float* __restrict__ cwg, float* __restrict__ ST_) {
  __shared__ float red8[8][8];
  int blk = blockIdx.x, t = threadIdx.x;
  int b = blk >> 2, seg = blk & 3;
  int n = seg * 512 + t;
  int lane = t & 63, wv = t >> 6;
  float agv = ag[b], wgv = wg[b], dw = denw[b];
  float4 r4 = *(const float4*)&rw[(size_t)(b * N + n) * R];
  float w = ww_inline(sw_[b * N + n], alloc_[b * N + n], dw, agv, wgv);
  float pc = prec[b * N + n];
  *(float4*)&cwg[(size_t)(b * N + n) * 8] = make_float4(r4.x, r4.y, r4.z, r4.w);
  *(float4*)&cwg[(size_t)(b * N + n) * 8 + 4] =
      make_float4(w * r4.x, w * r4.y, w * r4.z, w * r4.w);
  float a[8] = { pc * r4.x, pc * r4.y, pc * r4.z, pc * r4.w,
                 w * r4.x,  w * r4.y,  w * r4.z,  w * r4.w };
  #pragma unroll
  for (int r = 0; r < 8; r++) a[r] = wred_sum(a[r]);
  if (lane == 0) {
    #pragma unroll
    for (int r = 0; r < 8; r++) red8[wv][r] = a[r];
  }
  __syncthreads();
  if (t < 8) {
    float s = 0.f;
    #pragma unroll
    for (int i = 0; i < 8; i++) s += red8[i][t];
    atomicAdd(&ST_[b * 8 + t], s);
  }
}

// ---- K_mid: blocks 0..511 linkpass (32-row strips, single link pass, setup from cwg);
//             512..2559 phir
__global__ __launch_bounds__(512) void k_mid(const float* __restrict__ link,
    const float* __restrict__ rw, const float* __restrict__ sw_,
    const float* __restrict__ alloc_, const float* __restrict__ denw,
    const float* __restrict__ ag, const float* __restrict__ wg,
    const float* __restrict__ mem, const float* __restrict__ rk,
    const float* __restrict__ ev, const float* __restrict__ wvec,
    const float* __restrict__ rs, const float* __restrict__ cwg,
    float* __restrict__ t_, float* __restrict__ upart, float* __restrict__ sr_,
    float* __restrict__ denr) {
  __shared__ float tred[32][8][8];   // 8KB (linkpass)
  __shared__ float ri8l[32][8];      // 1KB (linkpass)
  __shared__ float eacc[8][4];       // (phir)
  const int blk = blockIdx.x;
  const int t = threadIdx.x;
  const int lane = t & 63, wv = t >> 6;
  if (blk < 512) {
    // ======== linkpass: 32-row strip, all 2048 columns, single link read ========
    const int b = blk >> 6;
    const int strip = blk & 63;
    const int i0 = strip * 32;
    const int jb = t * 4;
    // stage per-row ri (32 rows x 8) from cwg
    if (t < 256) ri8l[t >> 3][t & 7] = cwg[(size_t)(b * N + i0) * 8 + t];
    // per-thread column weights from cwg (4 columns x 8)
    float cw[4][8];
    #pragma unroll
    for (int k = 0; k < 4; k++) {
      float4 lo = *(const float4*)&cwg[(size_t)(b * N + jb + k) * 8];
      float4 hi = *(const float4*)&cwg[(size_t)(b * N + jb + k) * 8 + 4];
      cw[k][0] = lo.x; cw[k][1] = lo.y; cw[k][2] = lo.z; cw[k][3] = lo.w;
      cw[k][4] = hi.x; cw[k][5] = hi.y; cw[k][6] = hi.z; cw[k][7] = hi.w;
    }
    float uacc[4][8];
    #pragma unroll
    for (int k = 0; k < 4; k++) {
      #pragma unroll
      for (int r = 0; r < 8; r++) uacc[k][r] = 0.f;
    }
    __syncthreads();
    const float* Lbase = link + (size_t)(b * N + i0) * N;
    for (int ii = 0; ii < 32; ii += 4) {
      float4 La[4];
      #pragma unroll
      for (int m = 0; m < 4; m++)
        La[m] = *(const float4*)(Lbase + (size_t)(ii + m) * N + jb);
      #pragma unroll
      for (int m = 0; m < 4; m++) {
        float lv[4] = { La[m].x, La[m].y, La[m].z, La[m].w };
        float trow[8] = { 0, 0, 0, 0, 0, 0, 0, 0 };
        #pragma unroll
        for (int k = 0; k < 4; k++) {
          #pragma unroll
          for (int r = 0; r < 8; r++) {
            uacc[k][r] = fmaf(lv[k], ri8l[ii + m][r], uacc[k][r]);
            trow[r] = fmaf(lv[k], cw[k][r], trow[r]);
          }
        }
        // butterfly: lane l ends with sum over 64 lanes of trow[l&7]
        float nv[4];
        #pragma unroll
        for (int rr = 0; rr < 4; rr++) {
          float a = trow[2 * rr], c = trow[2 * rr + 1];
          float oa = __shfl_xor(a, 1, 64), oc = __shfl_xor(c, 1, 64);
          nv[rr] = (lane & 1) ? (c + oc) : (a + oa);
        }
        float nw[2];
        #pragma unroll
        for (int rr = 0; rr < 2; rr++) {
          float a = nv[2 * rr], c = nv[2 * rr + 1];
          float oa = __shfl_xor(a, 2, 64), oc = __shfl_xor(c, 2, 64);
          nw[rr] = (lane & 2) ? (c + oc) : (a + oa);
        }
        float a2 = nw[0], c2 = nw[1];
        float oa2 = __shfl_xor(a2, 4, 64), oc2 = __shfl_xor(c2, 4, 64);
        float vv = (lane & 4) ? (c2 + oc2) : (a2 + oa2);
        vv += __shfl_xor(vv, 8, 64);
        vv += __shfl_xor(vv, 16, 64);
        vv += __shfl_xor(vv, 32, 64);
        if (lane < 8) tred[ii + m][wv][lane] = vv;
      }
    }
    __syncthreads();
    if (t < 256) {
      int i = t >> 3, r = t & 7;     // 32 rows x 8 r
      float s = 0.f;
      #pragma unroll
      for (int w8 = 0; w8 < 8; w8++) s += tred[i][w8][r];
      t_[((size_t)(b * 8 + r)) * N + i0 + i] = s;   // [b][r8][n]
    }
    // upart [b][strip64][r8][n]
    float* ubp = upart + ((size_t)(b * 64 + strip) * 8) * N;
    #pragma unroll
    for (int r = 0; r < 8; r++) {
      float4 v = { uacc[0][r], uacc[1][r], uacc[2][r], uacc[3][r] };
      *(float4*)(ubp + (size_t)r * N + jb) = v;
    }
  } else {
    // ======== phir: 8 rows per block + denr atomics ========
    int gw = (blk - 512) * 8 + wv;
    int b = gw >> 11, n = gw & (N - 1);
    const float agv = ag[b], wgv = wg[b], dw = denw[b];
    float w = ww_inline(sw_[b * N + n], alloc_[b * N + n], dw, agv, wgv);
    int c0i = lane * 4;
    float4 m4 = *(const float4*)&mem[(size_t)(b * N + n) * C + c0i];
    float4 e4 = *(const float4*)&ev[b * C + c0i];
    float4 v4 = *(const float4*)&wvec[b * C + c0i];
    float mn[4] = { m4.x * (1.f - w * e4.x) + w * v4.x,
                    m4.y * (1.f - w * e4.y) + w * v4.y,
                    m4.z * (1.f - w * e4.z) + w * v4.z,
                    m4.w * (1.f - w * e4.w) + w * v4.w };
    float dot[4] = { 0, 0, 0, 0 };
    float kn[4] = { 0, 0, 0, 0 };
    float nrm = 0.f;
    #pragma unroll
    for (int ci = 0; ci < 4; ci++) {
      float4 k4 = *(const float4*)&rk[(size_t)(b * C + c0i + ci) * R];
      dot[0] = fmaf(mn[ci], k4.x, dot[0]);
      dot[1] = fmaf(mn[ci], k4.y, dot[1]);
      dot[2] = fmaf(mn[ci], k4.z, dot[2]);
      dot[3] = fmaf(mn[ci], k4.w, dot[3]);
      kn[0] = fmaf(k4.x, k4.x, kn[0]);
      kn[1] = fmaf(k4.y, k4.y, kn[1]);
      kn[2] = fmaf(k4.z, k4.z, kn[2]);
      kn[3] = fmaf(k4.w, k4.w, kn[3]);
      nrm = fmaf(mn[ci], mn[ci], nrm);
    }
    for (int d = 32; d; d >>= 1) {
      dot[0] += __shfl_xor(dot[0], d, 64);
      dot[1] += __shfl_xor(dot[1], d, 64);
      dot[2] += __shfl_xor(dot[2], d, 64);
      dot[3] += __shfl_xor(dot[3], d, 64);
      kn[0] += __shfl_xor(kn[0], d, 64);
      kn[1] += __shfl_xor(kn[1], d, 64);
      kn[2] += __shfl_xor(kn[2], d, 64);
      kn[3] += __shfl_xor(kn[3], d, 64);
      nrm += __shfl_xor(nrm, d, 64);
    }
    if (lane == 0) {
      float mnorm = sqrtf(nrm);
      #pragma unroll
      for (int r = 0; r < 4; r++) {
        float phi = dot[r] / (mnorm * sqrtf(kn[r]) + EPS);
        float sv = phi * rs[b * R + r];
        sr_[(size_t)(b * R + r) * N + n] = sv;
        eacc[wv][r] = expf(sv);
      }
    }
    __syncthreads();
    if (t < 4) {
      float s = 0.f;
      #pragma unroll
      for (int i = 0; i < 8; i++) s += eacc[i][t];
      atomicAdd(&denr[b * R + t], s);
    }
  }
}

// ---- K_combread: strip-reduce u (64 strips), rwn in LDS, then read_vectors partials
__global__ __launch_bounds__(256) void k_combread(const float* __restrict__ link,
    const float* __restrict__ sw_, const float* __restrict__ alloc_,
    const float* __restrict__ denw, const float* __restrict__ denr,
    const float* __restrict__ ag, const float* __restrict__ wg,
    const float* __restrict__ prec, const float* __restrict__ rw,
    const float* __restrict__ t_, const float* __restrict__ upart,
    const float* __restrict__ sr_, const float* __restrict__ ST_,
    const float* __restrict__ modes, const float* __restrict__ mem,
    const float* __restrict__ ev, const float* __restrict__ wvec,
    float* __restrict__ part_) {
  __shared__ float dgl[64], wloc[64], rwnl[4][64];
  __shared__ float red[4][64][4][4];   // 16KB
  const int blk = blockIdx.x;
  const int b = blk >> 5, chunk = blk & 31;
  const int n0 = chunk * 64;
  const int t = threadIdx.x;
  const int nl = t & 63, r = t >> 6;
  const int n = n0 + nl;
  const float agv = ag[b], wgv = wg[b], dw = denw[b];
  float u1 = 0.f, u2 = 0.f;
  const float* up = upart + ((size_t)(b * 64) * 8) * N;
  #pragma unroll 8
  for (int s = 0; s < 64; s++) {
    const float* p = up + ((size_t)s * 8) * N;
    u1 += p[(size_t)r * N + n];
    u2 += p[(size_t)(4 + r) * N + n];
  }
  float pc = prec[b * N + n];
  if (r == 0) {
    float w = ww_inline(sw_[b * N + n], alloc_[b * N + n], dw, agv, wgv);
    float L = link[((size_t)(b * N + n)) * N + n];
    dgl[nl] = (1.f - 2.f * w) * L + w * pc;
    wloc[nl] = w;
  }
  __syncthreads();
  {
    float w = wloc[nl], Dg = dgl[nl];
    float t1 = t_[(size_t)(b * 8 + r) * N + n];
    float t2 = t_[(size_t)(b * 8 + 4 + r) * N + n];
    float sv = sr_[(size_t)(b * R + r) * N + n];
    float cr = expf(sv) / denr[b * R + r];
    float rv = rw[(size_t)(b * N + n) * R + r];
    float S = ST_[b * 8 + r], T = ST_[b * 8 + 4 + r];
    float m0 = modes[(b * 3 + 0) * R + r], m1 = modes[(b * 3 + 1) * R + r],
          m2 = modes[(b * 3 + 2) * R + r];
    float fwd = (1.f - w) * t1 - t2 + w * S - Dg * rv;
    float bwd = (1.f - w) * u1 - u2 + pc * T - Dg * rv;
    rwnl[r][nl] = m0 * bwd + m1 * cr + m2 * fwd;
  }
  __syncthreads();
  const int sub = r, cg = nl;
  const int c0 = cg * 4;
  float4 e4 = *(const float4*)&ev[b * C + c0];
  float4 v4 = *(const float4*)&wvec[b * C + c0];
  float acc[4][4];
  #pragma unroll
  for (int ci = 0; ci < 4; ci++) {
    #pragma unroll
    for (int rr = 0; rr < 4; rr++) acc[ci][rr] = 0.f;
  }
  for (int m = 0; m < 16; m++) {
    int row = sub * 16 + m;
    int nn = n0 + row;
    float w = wloc[row];
    float4 m4 = *(const float4*)&mem[(size_t)(b * N + nn) * C + c0];
    float mn[4] = { m4.x * (1.f - w * e4.x) + w * v4.x,
                    m4.y * (1.f - w * e4.y) + w * v4.y,
                    m4.z * (1.f - w * e4.z) + w * v4.z,
                    m4.w * (1.f - w * e4.w) + w * v4.w };
    float rv[4] = { rwnl[0][row], rwnl[1][row], rwnl[2][row], rwnl[3][row] };
    #pragma unroll
    for (int ci = 0; ci < 4; ci++) {
      #pragma unroll
      for (int rr = 0; rr < 4; rr++) acc[ci][rr] = fmaf(mn[ci], rv[rr], acc[ci][rr]);
    }
  }
  #pragma unroll
  for (int ci = 0; ci < 4; ci++) {
    #pragma unroll
    for (int rr = 0; rr < 4; rr++) red[sub][cg][ci][rr] = acc[ci][rr];
  }
  __syncthreads();
  if (sub == 0) {
    #pragma unroll
    for (int ci = 0; ci < 4; ci++) {
      #pragma unroll
      for (int rr = 0; rr < 4; rr++) {
        float s = red[0][cg][ci][rr] + red[1][cg][ci][rr] +
                  red[2][cg][ci][rr] + red[3][cg][ci][rr];
        part_[((size_t)blk * C + (c0 + ci)) * R + rr] = s;
      }
    }
  }
}

// ---- K_final: reduce 32 chunk partials -> out [B][C][R]
__global__ void k_final(const float* __restrict__ part_, float* __restrict__ out) {
  int idx = blockIdx.x * 256 + threadIdx.x;
  if (idx >= B * C * R) return;
  int b = idx / (C * R), cr = idx % (C * R);
  float s = 0.f;
  for (int ch = 0; ch < 32; ch++) s += part_[(size_t)(b * 32 + ch) * C * R + cr];
  out[idx] = s;
}

extern "C" void kernel_launch(void* const* d_in, const int* in_sizes, int n_in,
                              void* d_out, int out_size, void* d_ws, size_t ws_size,
                              hipStream_t stream) {
  const float* mem   = (const float*)d_in[0];
  const float* link  = (const float*)d_in[1];
  const float* usage = (const float*)d_in[2];
  const float* rw    = (const float*)d_in[3];
  const float* wwp   = (const float*)d_in[4];
  const float* prec  = (const float*)d_in[5];
  const float* rk    = (const float*)d_in[6];
  const float* rs    = (const float*)d_in[7];
  const float* wk    = (const float*)d_in[8];
  const float* wstr  = (const float*)d_in[9];
  const float* fg    = (const float*)d_in[10];
  const float* ag    = (const float*)d_in[11];
  const float* wg    = (const float*)d_in[12];
  const float* wvec  = (const float*)d_in[13];
  const float* ev    = (const float*)d_in[14];
  const float* modes = (const float*)d_in[15];
  float* out = (float*)d_out;

  float* W = (float*)d_ws;
  float* denw  = W;                   // 8
  float* denr  = W + 8;               // 32
  float* ST_   = W + 64;              // 64   (zeroed below)
  float* alloc_= W + 128;             // B*N
  float* sw_   = alloc_ + B * N;      // B*N
  float* t_    = sw_ + B * N;         // B*8*N
  float* sr_   = t_ + B * 8 * N;      // B*R*N
  float* part_ = sr_ + B * R * N;     // B*32*C*R
  float* cwg   = part_ + B * 32 * C * R;  // B*N*8
  float* upart = cwg + B * N * 8;     // B*64*8*N = 32MB

  (void)hipMemsetAsync(W, 0, 128 * sizeof(float), stream);
  k_pre<<<256 + (B * N) / 16, 1024, 0, stream>>>(usage, wwp, fg, rw, mem, wk, wstr,
                                                 alloc_, sw_, denw);
  k_cw<<<B * 4, 512, 0, stream>>>(rw, sw_, alloc_, denw, ag, wg, prec, cwg, ST_);
  k_mid<<<512 + (B * N) / 8, 512, 0, stream>>>(link, rw, sw_, alloc_, denw, ag, wg,
                                               mem, rk, ev, wvec, rs, cwg,
                                               t_, upart, sr_, denr);
  k_combread<<<B * 32, 256, 0, stream>>>(link, sw_, alloc_, denw, denr, ag, wg, prec,
                                         rw, t_, upart, sr_, ST_, modes, mem, ev,
                                         wvec, part_);
  k_final<<<(B * C * R) / 256, 256, 0, stream>>>(part_, out);
}